// Round 11
// baseline (369.445 us; speedup 1.0000x reference)
//
#include <hip/hip_runtime.h>
#include <hip/hip_bf16.h>

typedef __attribute__((ext_vector_type(8))) short bf16x8;
typedef __attribute__((ext_vector_type(4))) float f32x4;
typedef unsigned short ushort_t;
typedef __attribute__((ext_vector_type(4))) unsigned short ush4;

__device__ inline ushort_t f2bf(float f){
    union { float f; unsigned int u; } v; v.f = f;
    unsigned int r = v.u + 0x7fffu + ((v.u >> 16) & 1u);   // RNE
    return (ushort_t)(r >> 16);
}
__device__ inline float bf2f(ushort_t u){
    union { unsigned int i; float f; } v; v.i = ((unsigned int)u) << 16; return v.f;
}

__device__ inline void gload_lds16(const void* g, void* l){
    __builtin_amdgcn_global_load_lds(
        (const __attribute__((address_space(1))) unsigned int*)g,
        (__attribute__((address_space(3))) unsigned int*)l, 16, 0, 0);
}

// ---------------- weight transforms ----------------
// prim_w [256 oc][256 ic][81 p] f32  ->  w2t [oc][p][ic] bf16
__global__ __launch_bounds__(256) void k_w2t(const float* __restrict__ pw, ushort_t* __restrict__ w2t)
{
    __shared__ float tile[5184];             // [64 ic][81 p]
    const int oc  = blockIdx.x >> 2;
    const int ic0 = (blockIdx.x & 3) * 64;
    const float* src = pw + (oc*256 + ic0)*81;
    for (int j = threadIdx.x; j < 5184; j += 256) tile[j] = src[j];
    __syncthreads();
    for (int j = threadIdx.x; j < 5184; j += 256){
        int p = j >> 6, ic = j & 63;
        w2t[(oc*81 + p)*256 + ic0 + ic] = f2bf(tile[ic*81 + p]);
    }
}

// conv_w [256 oc][243 k] f32 -> cwb [oc][256] bf16, zero-padded k 243..255
__global__ __launch_bounds__(256) void k_cwb(const float* __restrict__ cw, ushort_t* __restrict__ cwb){
    const int oc = blockIdx.x;    // 0..255
    const int k  = threadIdx.x;   // 0..255
    cwb[oc*256 + k] = (k < 243) ? f2bf(cw[oc*243 + k]) : (ushort_t)0;
}

// ---------------- conv1 as bf16 MFMA GEMM (im2col from x) -----------------------
__global__ __launch_bounds__(256) void k_conv1m(const float* __restrict__ x,
    const ushort_t* __restrict__ cwb, const float* __restrict__ conv_b,
    ushort_t* __restrict__ ht)
{
    __shared__ ushort_t At[8192];   // 16 KB
    __shared__ ushort_t Bt[8192];   // 16 KB
    const int tid = threadIdx.x;
    const int bid = blockIdx.x;          // 1152
    const int mt = bid >> 1, nt = bid & 1;
    const int m0 = mt*128, n0 = nt*128;
    const int lane = tid & 63, wave = tid >> 6;
    const int wm = (wave >> 1)*64, wn = (wave & 1)*64;
    const int l16 = lane & 15, lq = lane >> 4;
    const int rx = l16 & 7;

    int xbase[4], aoff[4], swz[4];
    const ushort_t* bsrc[4];
    #pragma unroll
    for (int t=0;t<4;t++){
        const int cid = tid + t*256;
        const int row = cid >> 3, co = cid & 7;
        swz[t] = (row*8 + (co ^ (row & 7)))*8;
        aoff[t] = co*8;
        const int m = m0 + row;
        const int b = m / 576, rem = m - b*576;
        const int oy = rem / 24, ox = rem - oy*24;
        xbase[t] = b*3072 + oy*32 + ox;
        bsrc[t] = cwb + (n0 + row)*256 + co*8;
    }

    f32x4 acc[4][4];
    #pragma unroll
    for (int i=0;i<4;i++)
        #pragma unroll
        for (int j=0;j<4;j++) acc[i][j] = 0;

    for (int step = 0; step < 4; step++){
        const int k0 = step*64;
        #pragma unroll
        for (int t=0;t<4;t++){
            union { ushort_t u[8]; bf16x8 v; } pk;
            #pragma unroll
            for (int j=0;j<8;j++){
                const int k = k0 + aoff[t] + j;
                float val = 0.f;
                if (k < 243){
                    const int ic = k / 81, p = k - ic*81;
                    const int ky = p / 9, kx = p - ky*9;
                    val = x[xbase[t] + ic*1024 + ky*32 + kx];
                }
                pk.u[j] = f2bf(val);
            }
            *(bf16x8*)&At[swz[t]] = pk.v;
        }
        #pragma unroll
        for (int t=0;t<4;t++){
            bf16x8 v = *(const bf16x8*)(bsrc[t] + k0);
            *(bf16x8*)&Bt[swz[t]] = v;
        }
        __syncthreads();
        #pragma unroll
        for (int kk=0; kk<2; kk++){
            bf16x8 a[4], bb[4];
            const int cs = ((kk*4 + lq) ^ rx)*8;
            #pragma unroll
            for (int f=0; f<4; f++){
                a[f]  = *(const bf16x8*)&At[(wm + f*16 + l16)*64 + cs];
                bb[f] = *(const bf16x8*)&Bt[(wn + f*16 + l16)*64 + cs];
            }
            #pragma unroll
            for (int i=0;i<4;i++)
                #pragma unroll
                for (int j=0;j<4;j++)
                    acc[i][j] = __builtin_amdgcn_mfma_f32_16x16x32_bf16(a[i], bb[j], acc[i][j], 0,0,0);
        }
        __syncthreads();
    }
    #pragma unroll
    for (int j=0;j<4;j++){
        const int n = n0 + wn + j*16 + l16;
        const float bias = conv_b[n];
        #pragma unroll
        for (int i=0;i<4;i++)
            #pragma unroll
            for (int r=0;r<4;r++){
                const int m = m0 + wm + i*16 + lq*4 + r;
                float v = acc[i][j][r] + bias;
                v = v > 0.f ? v : 0.01f*v;
                ht[(size_t)m*256 + n] = f2bf(v);
            }
    }
}

// ---------------- conv2: MFMA GEMM, SINGLE-buffer, mt-affine XCD map ------------
__global__ __launch_bounds__(256) void k_conv2gemm(const ushort_t* __restrict__ ht,
    const ushort_t* __restrict__ w2t, float* __restrict__ p2p)
{
    __shared__ ushort_t At[8192];   // 16 KB
    __shared__ ushort_t Bt[8192];   // 16 KB
    const int tid = threadIdx.x;
    const int bid = blockIdx.x;              // 512 blocks
    const int mt = bid & 63, rest = bid >> 6;
    const int nt = rest & 1, ks = rest >> 1;
    const int m0 = mt*128, n0 = nt*128;
    const int lane = tid & 63, wave = tid >> 6;
    const int wm = (wave >> 1)*64, wn = (wave & 1)*64;
    const int l16 = lane & 15, lq = lane >> 4;
    const int rx = l16 & 7;

    const int srow0 = wave*32 + (lane >> 3);
    const int cop = lane & 7;
    const ushort_t* asrc[4];
    const ushort_t* bsrc[4];
    #pragma unroll
    for (int t = 0; t < 4; t++){
        const int row = srow0 + t*8;
        const int col = cop ^ (row & 7);
        const int m = m0 + row;
        const int bi = m >> 6, hw = m & 63;
        const int oy2 = hw >> 3, ox2 = hw & 7;
        asrc[t] = ht + (((bi*24 + 2*oy2)*24) + 2*ox2)*256 + col*8;
        bsrc[t] = w2t + (size_t)(n0 + row)*20736 + col*8;
    }

    f32x4 acc[4][4];
    #pragma unroll
    for (int i=0;i<4;i++)
        #pragma unroll
        for (int j=0;j<4;j++) acc[i][j] = 0;

    const int k_begin = ks*5184;
    for (int step = 0; step < 81; step++){
        const int k0 = k_begin + step*64;
        const int pq = k0 >> 8;
        const int ky = pq/9, kx = pq - ky*9;
        const int aoff = (ky*24 + kx)*256 + (k0 & 255);
        #pragma unroll
        for (int t=0;t<4;t++){
            gload_lds16(asrc[t] + aoff, &At[(wave*4+t)*512]);
            gload_lds16(bsrc[t] + k0,  &Bt[(wave*4+t)*512]);
        }
        __syncthreads();
        #pragma unroll
        for (int kk=0; kk<2; kk++){
            bf16x8 a[4], bb[4];
            const int cs = ((kk*4 + lq) ^ rx)*8;
            #pragma unroll
            for (int f=0; f<4; f++){
                a[f]  = *(const bf16x8*)&At[(wm + f*16 + l16)*64 + cs];
                bb[f] = *(const bf16x8*)&Bt[(wn + f*16 + l16)*64 + cs];
            }
            #pragma unroll
            for (int i=0;i<4;i++)
                #pragma unroll
                for (int j=0;j<4;j++)
                    acc[i][j] = __builtin_amdgcn_mfma_f32_16x16x32_bf16(a[i], bb[j], acc[i][j], 0,0,0);
        }
        __syncthreads();
    }
    float* dst = p2p + (size_t)ks*2097152;
    #pragma unroll
    for (int i=0;i<4;i++)
        #pragma unroll
        for (int j=0;j<4;j++)
            #pragma unroll
            for (int r=0;r<4;r++){
                const int m = m0 + wm + i*16 + lq*4 + r;
                const int n = n0 + wn + j*16 + l16;
                dst[m*256 + n] = acc[i][j][r];
            }
}

// ---------------- p (+bias) -> u (squashed), layout u_r[n][b][8] ----------------
__global__ __launch_bounds__(256) void k_squash_u(const float* __restrict__ p2p,
    const float* __restrict__ prim_b, float* __restrict__ u)
{
    const int idx = blockIdx.x*256 + threadIdx.x;  // 0..262143 = b*2048+n
    const int b = idx >> 11, n = idx & 2047;
    const int hw = n >> 5, cap = n & 31;
    const int base = (b*64 + hw)*256 + cap*8;
    float v[8];
    #pragma unroll
    for (int j=0;j<8;j++) v[j] = prim_b[cap*8+j];
    #pragma unroll
    for (int ksp=0; ksp<4; ksp++){
        const float* sp = p2p + (size_t)ksp*2097152 + base;
        #pragma unroll
        for (int j=0;j<8;j++) v[j] += sp[j];
    }
    float s = 0.f;
    #pragma unroll
    for (int j=0;j<8;j++) s += v[j]*v[j];
    const float sc = sqrtf(s)/(1.0f + s);
    float* dst = u + ((size_t)n*128 + b)*8;
    #pragma unroll
    for (int j=0;j<8;j++) dst[j] = v[j]*sc;
}

// ---------------- pass-1 fast path: part0[ns][b][cd] = sum_{n in chunk} uhat ----
// grid (c=10, ns=64), 128 thr. Thread: bg=tid>>2 owns b=bg*4..+3, dq=tid&3 owns 4 d.
// W chunk (32 nodes, 16 KB) staged once; per (n,i): 1 ds_read_b128 -> 16 fma.
__global__ __launch_bounds__(128) void k_uhat0(const float* __restrict__ u_r,
    const float* __restrict__ dw, float* __restrict__ part0)
{
    __shared__ float Wl[4096];              // [n_l*128 + i*16 + d]
    const int tid = threadIdx.x;
    const int c = blockIdx.x, ns = blockIdx.y;
    const int n0 = ns*32;
    const float* wsrc = dw + (size_t)(c*2048 + n0)*128;
    for (int s = tid; s < 1024; s += 128)
        *(f32x4*)&Wl[s*4] = *(const f32x4*)(wsrc + s*4);
    __syncthreads();
    const int bg = tid >> 2, dq = tid & 3;
    float acc[4][4];                         // [kb][dd]
    #pragma unroll
    for (int kb=0;kb<4;kb++)
        #pragma unroll
        for (int dd=0;dd<4;dd++) acc[kb][dd] = 0.f;
    for (int n = 0; n < 32; n++){
        float uu[4][8];
        const float* up = u_r + ((size_t)(n0+n)*128 + bg*4)*8;
        #pragma unroll
        for (int kb=0;kb<4;kb++){
            *(f32x4*)&uu[kb][0] = *(const f32x4*)(up + kb*8);
            *(f32x4*)&uu[kb][4] = *(const f32x4*)(up + kb*8 + 4);
        }
        #pragma unroll
        for (int i=0;i<8;i++){
            const f32x4 wv = *(const f32x4*)&Wl[n*128 + i*16 + dq*4];
            #pragma unroll
            for (int kb=0;kb<4;kb++)
                #pragma unroll
                for (int dd=0;dd<4;dd++)
                    acc[kb][dd] = fmaf(wv[dd], uu[kb][i], acc[kb][dd]);
        }
    }
    #pragma unroll
    for (int kb=0;kb<4;kb++){
        f32x4 v;
        #pragma unroll
        for (int dd=0;dd<4;dd++) v[dd] = acc[kb][dd];
        *(f32x4*)(part0 + ((size_t)ns*128 + bg*4+kb)*160 + c*16 + dq*4) = v;
    }
}

// S[b][cd] = squash_d( 0.1 * sum_ns part0 )
__global__ __launch_bounds__(192) void k_red0(const float* __restrict__ part0,
    float* __restrict__ S)
{
    const int b = blockIdx.x;
    const int t = threadIdx.x;
    if (t >= 160) return;
    float s = 0.f;
    const float* base = part0 + (size_t)b*160 + t;
    #pragma unroll 8
    for (int ns=0; ns<64; ns++) s += base[(size_t)ns*20480];
    s *= 0.1f;
    float ss = s*s;
    ss += __shfl_xor(ss, 1, 16);
    ss += __shfl_xor(ss, 2, 16);
    ss += __shfl_xor(ss, 4, 16);
    ss += __shfl_xor(ss, 8, 16);
    S[b*160 + t] = s * sqrtf(ss)/(1.f+ss);
}

// ---------------- routing pass (route9): bf16 partials --------------------------
__global__ __launch_bounds__(256) void k_route9(const float* __restrict__ u_r,
    const float* __restrict__ dw, const float* __restrict__ S,
    ushort_t* __restrict__ partials)
{
    __shared__ float Wl[5120];              // ((n*10+c)*8+i)*16 + d
    const int tid = threadIdx.x;
    const int h = tid & 3;
    const int bq = tid >> 2;                // 0..63
    const int n0 = blockIdx.x * 4;
    for (int v = tid; v < 1280; v += 256){
        const int nc = v >> 5, ir = v & 31;
        const int i = ir >> 2, r4 = ir & 3;
        const int n = nc / 10, c = nc - n*10;
        *(f32x4*)&Wl[v*4] =
            *(const f32x4*)(dw + (size_t)(c*2048 + n0 + n)*128 + i*16 + r4*4);
    }
    __syncthreads();

    float oc[2][10][4];
    #pragma unroll
    for (int k=0;k<2;k++)
        #pragma unroll
        for (int c=0;c<10;c++)
            #pragma unroll
            for (int dd=0;dd<4;dd++) oc[k][c][dd] = 0.f;

    #pragma unroll
    for (int n=0;n<4;n++){
        float uu[2][8];
        #pragma unroll
        for (int k=0;k<2;k++){
            const float* up = u_r + ((size_t)(n0+n)*128 + bq + 64*k)*8;
            *(f32x4*)&uu[k][0] = *(const f32x4*)up;
            *(f32x4*)&uu[k][4] = *(const f32x4*)(up+4);
        }
        float ad[2][10][4];
        #pragma unroll
        for (int c=0;c<10;c++){
            const float* wp = &Wl[(n*10+c)*128 + h*4];
            #pragma unroll
            for (int k=0;k<2;k++)
                #pragma unroll
                for (int dd=0;dd<4;dd++) ad[k][c][dd] = 0.f;
            #pragma unroll
            for (int i=0;i<8;i++){
                const f32x4 wv = *(const f32x4*)(wp + i*16);   // one read, both k
                #pragma unroll
                for (int k=0;k<2;k++)
                    #pragma unroll
                    for (int dd=0;dd<4;dd++)
                        ad[k][c][dd] = fmaf(wv[dd], uu[k][i], ad[k][c][dd]);
            }
        }
        float p[2][10];
        #pragma unroll
        for (int k=0;k<2;k++){
            #pragma unroll
            for (int c=0;c<10;c++){
                const f32x4 sv = *(const f32x4*)(S + (bq+64*k)*160 + c*16 + h*4);
                float t = ad[k][c][0]*sv[0];
                t = fmaf(ad[k][c][1], sv[1], t);
                t = fmaf(ad[k][c][2], sv[2], t);
                t = fmaf(ad[k][c][3], sv[3], t);
                t += __shfl_xor(t, 1);        // quad d-sum
                t += __shfl_xor(t, 2);
                p[k][c] = t;                   // logit
            }
            float mx = p[k][0];
            #pragma unroll
            for (int c=1;c<10;c++) mx = fmaxf(mx, p[k][c]);
            float ssum = 0.f;
            #pragma unroll
            for (int c=0;c<10;c++){ p[k][c] = __expf(p[k][c]-mx); ssum += p[k][c]; }
            const float inv = 1.f/ssum;
            #pragma unroll
            for (int c=0;c<10;c++) p[k][c] *= inv;
        }
        #pragma unroll
        for (int k=0;k<2;k++)
            #pragma unroll
            for (int c=0;c<10;c++)
                #pragma unroll
                for (int dd=0;dd<4;dd++)
                    oc[k][c][dd] = fmaf(p[k][c], ad[k][c][dd], oc[k][c][dd]);
    }
    #pragma unroll
    for (int k=0;k<2;k++){
        ushort_t* dst = partials + ((size_t)blockIdx.x*128 + bq + 64*k)*160 + h*4;
        #pragma unroll
        for (int c=0;c<10;c++){
            ush4 v;
            #pragma unroll
            for (int dd=0;dd<4;dd++) v[dd] = f2bf(oc[k][c][dd]);
            *(ush4*)(dst + c*16) = v;
        }
    }
}

// out[b][c][d] = squash_d( sum_slots bf16 partials[sl][b][cd] )
// mode 1: S+=val, 2: out=val.  S layout [b][160].
__global__ __launch_bounds__(256) void k_reduce2h(const ushort_t* __restrict__ partials,
    float* __restrict__ S, float* __restrict__ outp, const int mode)
{
    const int c = blockIdx.x, b = blockIdx.y;
    const int t = threadIdx.x, d = t & 15, g = t >> 4;
    float s = 0.f;
    for (int sl = g; sl < 512; sl += 16)
        s += bf2f(partials[((size_t)sl*128 + b)*160 + c*16 + d]);
    __shared__ float red[256];
    red[t] = s;
    __syncthreads();
    if (g == 0){
        float v = red[d];
        #pragma unroll
        for (int k=1;k<16;k++) v += red[d + k*16];
        float ss = v*v;
        ss += __shfl_xor(ss, 1, 16);
        ss += __shfl_xor(ss, 2, 16);
        ss += __shfl_xor(ss, 4, 16);
        ss += __shfl_xor(ss, 8, 16);
        const float val = v * sqrtf(ss)/(1.f+ss);
        if (mode == 1) S[b*160 + c*16 + d] += val;
        else           outp[(b*10 + c)*16 + d] = val;
    }
}

extern "C" void kernel_launch(void* const* d_in, const int* in_sizes, int n_in,
                              void* d_out, int out_size, void* d_ws, size_t ws_size,
                              hipStream_t stream)
{
    const float* x      = (const float*)d_in[0];
    const float* conv_w = (const float*)d_in[1];
    const float* conv_b = (const float*)d_in[2];
    const float* prim_w = (const float*)d_in[3];
    const float* prim_b = (const float*)d_in[4];
    const float* dig_w  = (const float*)d_in[5];
    float* out = (float*)d_out;
    char* ws = (char*)d_ws;

    // layout (bytes). part0/partials/S overlay dead ht/w2t regions at routing time.
    ushort_t* ht       = (ushort_t*)(ws + 0);           // 37,748,736
    float*    part0    = (float*)   (ws + 0);           //  5,242,880 (overlay) [ns][b][160]
    ushort_t* partials = (ushort_t*)(ws + 0);           // 20,971,520 (overlay) [sl][b][160] bf16
    float*    S        = (float*)   (ws + 41943040);    //     81,920 (overlay) [b][160]
    ushort_t* w2t      = (ushort_t*)(ws + 37748736);    // 10,616,832
    ushort_t* cwb      = (ushort_t*)(ws + 48365568);    //    131,072
    float*    p2p      = (float*)   (ws + 48614400);    // 33,554,432
    float*    u        = (float*)   (ws + 82168832);    //  8,388,608  -> 90,557,440 total

    k_w2t<<<1024, 256, 0, stream>>>(prim_w, w2t);
    k_cwb<<<256, 256, 0, stream>>>(conv_w, cwb);
    k_conv1m<<<1152, 256, 0, stream>>>(x, cwb, conv_b, ht);
    k_conv2gemm<<<512, 256, 0, stream>>>(ht, w2t, p2p);
    k_squash_u<<<1024, 256, 0, stream>>>(p2p, prim_b, u);

    // pass 1 (uniform probs): dedicated GEMV path -> S = out_1
    k_uhat0<<<dim3(10,64), 128, 0, stream>>>(u, dig_w, part0);
    k_red0<<<128, 192, 0, stream>>>(part0, S);
    // passes 2..4: logits = uhat.S, softmax, out_k; S accumulates squashed outs
    k_route9<<<512, 256, 0, stream>>>(u, dig_w, S, partials);
    k_reduce2h<<<dim3(10,128), 256, 0, stream>>>(partials, S, out, 1);
    k_route9<<<512, 256, 0, stream>>>(u, dig_w, S, partials);
    k_reduce2h<<<dim3(10,128), 256, 0, stream>>>(partials, S, out, 1);
    k_route9<<<512, 256, 0, stream>>>(u, dig_w, S, partials);
    k_reduce2h<<<dim3(10,128), 256, 0, stream>>>(partials, S, out, 2);
}

// Round 12
// 316.191 us; speedup vs baseline: 1.1684x; 1.1684x over previous
//
#include <hip/hip_runtime.h>
#include <hip/hip_bf16.h>

typedef __attribute__((ext_vector_type(8))) short bf16x8;
typedef __attribute__((ext_vector_type(4))) float f32x4;
typedef unsigned short ushort_t;
typedef __attribute__((ext_vector_type(4))) unsigned short ush4;

__device__ inline ushort_t f2bf(float f){
    union { float f; unsigned int u; } v; v.f = f;
    unsigned int r = v.u + 0x7fffu + ((v.u >> 16) & 1u);   // RNE
    return (ushort_t)(r >> 16);
}
__device__ inline float bf2f(ushort_t u){
    union { unsigned int i; float f; } v; v.i = ((unsigned int)u) << 16; return v.f;
}

__device__ inline void gload_lds16(const void* g, void* l){
    __builtin_amdgcn_global_load_lds(
        (const __attribute__((address_space(1))) unsigned int*)g,
        (__attribute__((address_space(3))) unsigned int*)l, 16, 0, 0);
}

// ---------------- weight transforms ----------------
// prim_w [256 oc][256 ic][81 p] f32  ->  w2t [oc][p][ic] bf16
__global__ __launch_bounds__(256) void k_w2t(const float* __restrict__ pw, ushort_t* __restrict__ w2t)
{
    __shared__ float tile[5184];             // [64 ic][81 p]
    const int oc  = blockIdx.x >> 2;
    const int ic0 = (blockIdx.x & 3) * 64;
    const float* src = pw + (oc*256 + ic0)*81;
    for (int j = threadIdx.x; j < 5184; j += 256) tile[j] = src[j];
    __syncthreads();
    for (int j = threadIdx.x; j < 5184; j += 256){
        int p = j >> 6, ic = j & 63;
        w2t[(oc*81 + p)*256 + ic0 + ic] = f2bf(tile[ic*81 + p]);
    }
}

// conv_w [256 oc][243 k] f32 -> cwb [oc][256] bf16, zero-padded k 243..255
__global__ __launch_bounds__(256) void k_cwb(const float* __restrict__ cw, ushort_t* __restrict__ cwb){
    const int oc = blockIdx.x;    // 0..255
    const int k  = threadIdx.x;   // 0..255
    cwb[oc*256 + k] = (k < 243) ? f2bf(cw[oc*243 + k]) : (ushort_t)0;
}

// ---------------- conv1 as bf16 MFMA GEMM (im2col from x) -----------------------
__global__ __launch_bounds__(256) void k_conv1m(const float* __restrict__ x,
    const ushort_t* __restrict__ cwb, const float* __restrict__ conv_b,
    ushort_t* __restrict__ ht)
{
    __shared__ ushort_t At[8192];   // 16 KB
    __shared__ ushort_t Bt[8192];   // 16 KB
    const int tid = threadIdx.x;
    const int bid = blockIdx.x;          // 1152
    const int mt = bid >> 1, nt = bid & 1;
    const int m0 = mt*128, n0 = nt*128;
    const int lane = tid & 63, wave = tid >> 6;
    const int wm = (wave >> 1)*64, wn = (wave & 1)*64;
    const int l16 = lane & 15, lq = lane >> 4;
    const int rx = l16 & 7;

    int xbase[4], aoff[4], swz[4];
    const ushort_t* bsrc[4];
    #pragma unroll
    for (int t=0;t<4;t++){
        const int cid = tid + t*256;
        const int row = cid >> 3, co = cid & 7;
        swz[t] = (row*8 + (co ^ (row & 7)))*8;
        aoff[t] = co*8;
        const int m = m0 + row;
        const int b = m / 576, rem = m - b*576;
        const int oy = rem / 24, ox = rem - oy*24;
        xbase[t] = b*3072 + oy*32 + ox;
        bsrc[t] = cwb + (n0 + row)*256 + co*8;
    }

    f32x4 acc[4][4];
    #pragma unroll
    for (int i=0;i<4;i++)
        #pragma unroll
        for (int j=0;j<4;j++) acc[i][j] = 0;

    for (int step = 0; step < 4; step++){
        const int k0 = step*64;
        #pragma unroll
        for (int t=0;t<4;t++){
            union { ushort_t u[8]; bf16x8 v; } pk;
            #pragma unroll
            for (int j=0;j<8;j++){
                const int k = k0 + aoff[t] + j;
                float val = 0.f;
                if (k < 243){
                    const int ic = k / 81, p = k - ic*81;
                    const int ky = p / 9, kx = p - ky*9;
                    val = x[xbase[t] + ic*1024 + ky*32 + kx];
                }
                pk.u[j] = f2bf(val);
            }
            *(bf16x8*)&At[swz[t]] = pk.v;
        }
        #pragma unroll
        for (int t=0;t<4;t++){
            bf16x8 v = *(const bf16x8*)(bsrc[t] + k0);
            *(bf16x8*)&Bt[swz[t]] = v;
        }
        __syncthreads();
        #pragma unroll
        for (int kk=0; kk<2; kk++){
            bf16x8 a[4], bb[4];
            const int cs = ((kk*4 + lq) ^ rx)*8;
            #pragma unroll
            for (int f=0; f<4; f++){
                a[f]  = *(const bf16x8*)&At[(wm + f*16 + l16)*64 + cs];
                bb[f] = *(const bf16x8*)&Bt[(wn + f*16 + l16)*64 + cs];
            }
            #pragma unroll
            for (int i=0;i<4;i++)
                #pragma unroll
                for (int j=0;j<4;j++)
                    acc[i][j] = __builtin_amdgcn_mfma_f32_16x16x32_bf16(a[i], bb[j], acc[i][j], 0,0,0);
        }
        __syncthreads();
    }
    #pragma unroll
    for (int j=0;j<4;j++){
        const int n = n0 + wn + j*16 + l16;
        const float bias = conv_b[n];
        #pragma unroll
        for (int i=0;i<4;i++)
            #pragma unroll
            for (int r=0;r<4;r++){
                const int m = m0 + wm + i*16 + lq*4 + r;
                float v = acc[i][j][r] + bias;
                v = v > 0.f ? v : 0.01f*v;
                ht[(size_t)m*256 + n] = f2bf(v);
            }
    }
}

// ---------------- conv2: MFMA GEMM, SINGLE-buffer, mt-affine XCD map ------------
__global__ __launch_bounds__(256) void k_conv2gemm(const ushort_t* __restrict__ ht,
    const ushort_t* __restrict__ w2t, float* __restrict__ p2p)
{
    __shared__ ushort_t At[8192];   // 16 KB
    __shared__ ushort_t Bt[8192];   // 16 KB
    const int tid = threadIdx.x;
    const int bid = blockIdx.x;              // 512 blocks
    const int mt = bid & 63, rest = bid >> 6;
    const int nt = rest & 1, ks = rest >> 1;
    const int m0 = mt*128, n0 = nt*128;
    const int lane = tid & 63, wave = tid >> 6;
    const int wm = (wave >> 1)*64, wn = (wave & 1)*64;
    const int l16 = lane & 15, lq = lane >> 4;
    const int rx = l16 & 7;

    const int srow0 = wave*32 + (lane >> 3);
    const int cop = lane & 7;
    const ushort_t* asrc[4];
    const ushort_t* bsrc[4];
    #pragma unroll
    for (int t = 0; t < 4; t++){
        const int row = srow0 + t*8;
        const int col = cop ^ (row & 7);
        const int m = m0 + row;
        const int bi = m >> 6, hw = m & 63;
        const int oy2 = hw >> 3, ox2 = hw & 7;
        asrc[t] = ht + (((bi*24 + 2*oy2)*24) + 2*ox2)*256 + col*8;
        bsrc[t] = w2t + (size_t)(n0 + row)*20736 + col*8;
    }

    f32x4 acc[4][4];
    #pragma unroll
    for (int i=0;i<4;i++)
        #pragma unroll
        for (int j=0;j<4;j++) acc[i][j] = 0;

    const int k_begin = ks*5184;
    for (int step = 0; step < 81; step++){
        const int k0 = k_begin + step*64;
        const int pq = k0 >> 8;
        const int ky = pq/9, kx = pq - ky*9;
        const int aoff = (ky*24 + kx)*256 + (k0 & 255);
        #pragma unroll
        for (int t=0;t<4;t++){
            gload_lds16(asrc[t] + aoff, &At[(wave*4+t)*512]);
            gload_lds16(bsrc[t] + k0,  &Bt[(wave*4+t)*512]);
        }
        __syncthreads();
        #pragma unroll
        for (int kk=0; kk<2; kk++){
            bf16x8 a[4], bb[4];
            const int cs = ((kk*4 + lq) ^ rx)*8;
            #pragma unroll
            for (int f=0; f<4; f++){
                a[f]  = *(const bf16x8*)&At[(wm + f*16 + l16)*64 + cs];
                bb[f] = *(const bf16x8*)&Bt[(wn + f*16 + l16)*64 + cs];
            }
            #pragma unroll
            for (int i=0;i<4;i++)
                #pragma unroll
                for (int j=0;j<4;j++)
                    acc[i][j] = __builtin_amdgcn_mfma_f32_16x16x32_bf16(a[i], bb[j], acc[i][j], 0,0,0);
        }
        __syncthreads();
    }
    float* dst = p2p + (size_t)ks*2097152;
    #pragma unroll
    for (int i=0;i<4;i++)
        #pragma unroll
        for (int j=0;j<4;j++)
            #pragma unroll
            for (int r=0;r<4;r++){
                const int m = m0 + wm + i*16 + lq*4 + r;
                const int n = n0 + wn + j*16 + l16;
                dst[m*256 + n] = acc[i][j][r];
            }
}

// ---------------- p (+bias) -> u (squashed), layout u_r[n][b][8] ----------------
__global__ __launch_bounds__(256) void k_squash_u(const float* __restrict__ p2p,
    const float* __restrict__ prim_b, float* __restrict__ u)
{
    const int idx = blockIdx.x*256 + threadIdx.x;  // 0..262143 = b*2048+n
    const int b = idx >> 11, n = idx & 2047;
    const int hw = n >> 5, cap = n & 31;
    const int base = (b*64 + hw)*256 + cap*8;
    float v[8];
    #pragma unroll
    for (int j=0;j<8;j++) v[j] = prim_b[cap*8+j];
    #pragma unroll
    for (int ksp=0; ksp<4; ksp++){
        const float* sp = p2p + (size_t)ksp*2097152 + base;
        #pragma unroll
        for (int j=0;j<8;j++) v[j] += sp[j];
    }
    float s = 0.f;
    #pragma unroll
    for (int j=0;j<8;j++) s += v[j]*v[j];
    const float sc = sqrtf(s)/(1.0f + s);
    float* dst = u + ((size_t)n*128 + b)*8;
    #pragma unroll
    for (int j=0;j<8;j++) dst[j] = v[j]*sc;
}

// ---------------- pass-1 fast path: part0[ns][b][cd] = sum_{n in chunk} uhat ----
__global__ __launch_bounds__(128) void k_uhat0(const float* __restrict__ u_r,
    const float* __restrict__ dw, float* __restrict__ part0)
{
    __shared__ float Wl[4096];              // [n_l*128 + i*16 + d]
    const int tid = threadIdx.x;
    const int c = blockIdx.x, ns = blockIdx.y;
    const int n0 = ns*32;
    const float* wsrc = dw + (size_t)(c*2048 + n0)*128;
    for (int s = tid; s < 1024; s += 128)
        *(f32x4*)&Wl[s*4] = *(const f32x4*)(wsrc + s*4);
    __syncthreads();
    const int bg = tid >> 2, dq = tid & 3;
    float acc[4][4];                         // [kb][dd]
    #pragma unroll
    for (int kb=0;kb<4;kb++)
        #pragma unroll
        for (int dd=0;dd<4;dd++) acc[kb][dd] = 0.f;
    for (int n = 0; n < 32; n++){
        float uu[4][8];
        const float* up = u_r + ((size_t)(n0+n)*128 + bg*4)*8;
        #pragma unroll
        for (int kb=0;kb<4;kb++){
            *(f32x4*)&uu[kb][0] = *(const f32x4*)(up + kb*8);
            *(f32x4*)&uu[kb][4] = *(const f32x4*)(up + kb*8 + 4);
        }
        #pragma unroll
        for (int i=0;i<8;i++){
            const f32x4 wv = *(const f32x4*)&Wl[n*128 + i*16 + dq*4];
            #pragma unroll
            for (int kb=0;kb<4;kb++)
                #pragma unroll
                for (int dd=0;dd<4;dd++)
                    acc[kb][dd] = fmaf(wv[dd], uu[kb][i], acc[kb][dd]);
        }
    }
    #pragma unroll
    for (int kb=0;kb<4;kb++){
        f32x4 v;
        #pragma unroll
        for (int dd=0;dd<4;dd++) v[dd] = acc[kb][dd];
        *(f32x4*)(part0 + ((size_t)ns*128 + bg*4+kb)*160 + c*16 + dq*4) = v;
    }
}

// S[b][cd] = squash_d( 0.1 * sum_ns part0 )
__global__ __launch_bounds__(192) void k_red0(const float* __restrict__ part0,
    float* __restrict__ S)
{
    const int b = blockIdx.x;
    const int t = threadIdx.x;
    if (t >= 160) return;
    float s = 0.f;
    const float* base = part0 + (size_t)b*160 + t;
    #pragma unroll 8
    for (int ns=0; ns<64; ns++) s += base[(size_t)ns*20480];
    s *= 0.1f;
    float ss = s*s;
    ss += __shfl_xor(ss, 1, 16);
    ss += __shfl_xor(ss, 2, 16);
    ss += __shfl_xor(ss, 4, 16);
    ss += __shfl_xor(ss, 8, 16);
    S[b*160 + t] = s * sqrtf(ss)/(1.f+ss);
}

// ---------------- routing pass (route11): high-occupancy re-tile ----------------
// grid (512 n-chunks, 4 b-quarters) x 128 thr. Thread: h=tid&3 owns d=h*4..+3,
// bq=tid>>2 owns ONE b = q*32+bq. Per n: ad[10][4] computed once (persist),
// logits via ad.S + 2 quad shuffles, softmax in regs, oc += p*ad.
// ~110 VGPR -> 4 waves/SIMD; 8 blocks/CU (Wl 20KB x 8 = 160KB LDS exactly).
// partials slot-major [512][b][160] bf16 (b-quarters write disjoint rows).
__global__ __launch_bounds__(128) void k_route11(const float* __restrict__ u_r,
    const float* __restrict__ dw, const float* __restrict__ S,
    ushort_t* __restrict__ partials)
{
    __shared__ float Wl[5120];              // ((n*10+c)*8+i)*16 + d
    const int tid = threadIdx.x;
    const int h = tid & 3;
    const int bq = tid >> 2;                // 0..31
    const int nc = blockIdx.x;              // 0..511
    const int b  = blockIdx.y*32 + bq;
    const int n0 = nc*4;
    for (int v = tid; v < 1280; v += 128){
        const int ncc = v >> 5, ir = v & 31;
        const int i = ir >> 2, r4 = ir & 3;
        const int n = ncc / 10, c = ncc - n*10;
        *(f32x4*)&Wl[v*4] =
            *(const f32x4*)(dw + (size_t)(c*2048 + n0 + n)*128 + i*16 + r4*4);
    }
    __syncthreads();

    float oc[10][4];
    #pragma unroll
    for (int c=0;c<10;c++)
        #pragma unroll
        for (int dd=0;dd<4;dd++) oc[c][dd] = 0.f;

    #pragma unroll
    for (int n=0;n<4;n++){
        float uu[8];
        const float* up = u_r + ((size_t)(n0+n)*128 + b)*8;
        *(f32x4*)&uu[0] = *(const f32x4*)up;
        *(f32x4*)&uu[4] = *(const f32x4*)(up+4);

        float ad[10][4];
        #pragma unroll
        for (int c=0;c<10;c++){
            const float* wp = &Wl[(n*10+c)*128 + h*4];
            float a0=0.f, a1=0.f, a2=0.f, a3=0.f;
            #pragma unroll
            for (int i=0;i<8;i++){
                const f32x4 wv = *(const f32x4*)(wp + i*16);
                a0 = fmaf(wv[0], uu[i], a0);
                a1 = fmaf(wv[1], uu[i], a1);
                a2 = fmaf(wv[2], uu[i], a2);
                a3 = fmaf(wv[3], uu[i], a3);
            }
            ad[c][0]=a0; ad[c][1]=a1; ad[c][2]=a2; ad[c][3]=a3;
        }
        float p[10];
        #pragma unroll
        for (int c=0;c<10;c++){
            const f32x4 sv = *(const f32x4*)(S + b*160 + c*16 + h*4);
            float t = ad[c][0]*sv[0];
            t = fmaf(ad[c][1], sv[1], t);
            t = fmaf(ad[c][2], sv[2], t);
            t = fmaf(ad[c][3], sv[3], t);
            t += __shfl_xor(t, 1);            // quad d-sum
            t += __shfl_xor(t, 2);
            p[c] = t;                          // logit
        }
        float mx = p[0];
        #pragma unroll
        for (int c=1;c<10;c++) mx = fmaxf(mx, p[c]);
        float ssum = 0.f;
        #pragma unroll
        for (int c=0;c<10;c++){ p[c] = __expf(p[c]-mx); ssum += p[c]; }
        const float inv = 1.f/ssum;
        #pragma unroll
        for (int c=0;c<10;c++)
            #pragma unroll
            for (int dd=0;dd<4;dd++)
                oc[c][dd] = fmaf(p[c]*inv, ad[c][dd], oc[c][dd]);
    }
    ushort_t* dst = partials + ((size_t)nc*128 + b)*160 + h*4;
    #pragma unroll
    for (int c=0;c<10;c++){
        ush4 v;
        #pragma unroll
        for (int dd=0;dd<4;dd++) v[dd] = f2bf(oc[c][dd]);
        *(ush4*)(dst + c*16) = v;
    }
}

// out[b][c][d] = squash_d( sum_slots bf16 partials[sl][b][cd] )
// mode 1: S+=val, 2: out=val.  S layout [b][160].
__global__ __launch_bounds__(256) void k_reduce2h(const ushort_t* __restrict__ partials,
    float* __restrict__ S, float* __restrict__ outp, const int mode)
{
    const int c = blockIdx.x, b = blockIdx.y;
    const int t = threadIdx.x, d = t & 15, g = t >> 4;
    float s = 0.f;
    for (int sl = g; sl < 512; sl += 16)
        s += bf2f(partials[((size_t)sl*128 + b)*160 + c*16 + d]);
    __shared__ float red[256];
    red[t] = s;
    __syncthreads();
    if (g == 0){
        float v = red[d];
        #pragma unroll
        for (int k=1;k<16;k++) v += red[d + k*16];
        float ss = v*v;
        ss += __shfl_xor(ss, 1, 16);
        ss += __shfl_xor(ss, 2, 16);
        ss += __shfl_xor(ss, 4, 16);
        ss += __shfl_xor(ss, 8, 16);
        const float val = v * sqrtf(ss)/(1.f+ss);
        if (mode == 1) S[b*160 + c*16 + d] += val;
        else           outp[(b*10 + c)*16 + d] = val;
    }
}

extern "C" void kernel_launch(void* const* d_in, const int* in_sizes, int n_in,
                              void* d_out, int out_size, void* d_ws, size_t ws_size,
                              hipStream_t stream)
{
    const float* x      = (const float*)d_in[0];
    const float* conv_w = (const float*)d_in[1];
    const float* conv_b = (const float*)d_in[2];
    const float* prim_w = (const float*)d_in[3];
    const float* prim_b = (const float*)d_in[4];
    const float* dig_w  = (const float*)d_in[5];
    float* out = (float*)d_out;
    char* ws = (char*)d_ws;

    // layout (bytes). part0/partials/S overlay dead ht/w2t regions at routing time.
    ushort_t* ht       = (ushort_t*)(ws + 0);           // 37,748,736
    float*    part0    = (float*)   (ws + 0);           //  5,242,880 (overlay) [ns][b][160]
    ushort_t* partials = (ushort_t*)(ws + 0);           // 20,971,520 (overlay) [sl][b][160] bf16
    float*    S        = (float*)   (ws + 41943040);    //     81,920 (overlay) [b][160]
    ushort_t* w2t      = (ushort_t*)(ws + 37748736);    // 10,616,832
    ushort_t* cwb      = (ushort_t*)(ws + 48365568);    //    131,072
    float*    p2p      = (float*)   (ws + 48614400);    // 33,554,432
    float*    u        = (float*)   (ws + 82168832);    //  8,388,608  -> 90,557,440 total

    k_w2t<<<1024, 256, 0, stream>>>(prim_w, w2t);
    k_cwb<<<256, 256, 0, stream>>>(conv_w, cwb);
    k_conv1m<<<1152, 256, 0, stream>>>(x, cwb, conv_b, ht);
    k_conv2gemm<<<512, 256, 0, stream>>>(ht, w2t, p2p);
    k_squash_u<<<1024, 256, 0, stream>>>(p2p, prim_b, u);

    // pass 1 (uniform probs): dedicated GEMV path -> S = out_1
    k_uhat0<<<dim3(10,64), 128, 0, stream>>>(u, dig_w, part0);
    k_red0<<<128, 192, 0, stream>>>(part0, S);
    // passes 2..4: logits = uhat.S, softmax, out_k; S accumulates squashed outs
    k_route11<<<dim3(512,4), 128, 0, stream>>>(u, dig_w, S, partials);
    k_reduce2h<<<dim3(10,128), 256, 0, stream>>>(partials, S, out, 1);
    k_route11<<<dim3(512,4), 128, 0, stream>>>(u, dig_w, S, partials);
    k_reduce2h<<<dim3(10,128), 256, 0, stream>>>(partials, S, out, 1);
    k_route11<<<dim3(512,4), 128, 0, stream>>>(u, dig_w, S, partials);
    k_reduce2h<<<dim3(10,128), 256, 0, stream>>>(partials, S, out, 2);
}